// Round 6
// baseline (120.498 us; speedup 1.0000x reference)
//
#include <hip/hip_runtime.h>
#include <hip/hip_bf16.h>

#define S_LEN 2048
#define DH    64
#define NBH   32          // B*H
#define KVT   32          // keys per tile
#define NT    64          // tiles per bh (S/KVT)

typedef __attribute__((ext_vector_type(8)))  short short8;
typedef __attribute__((ext_vector_type(4)))  float f32x4;
typedef __attribute__((ext_vector_type(16))) float f32x16;

static __device__ __forceinline__ unsigned cvtpk_bf16(float a, float b) {
    unsigned r;
    asm("v_cvt_pk_bf16_f32 %0, %1, %2" : "=v"(r) : "v"(a), "v"(b));
    return r;
}
// cross-half (lane ^ 32) reductions — __shfl_xor is proven on this target.
// (The permlane32_swap version with two identical "+v" operands was register-
//  coalesced into `v_permlane32_swap_b32 v5, v5`, dropping each lane's own
//  half -> l_run could collapse to 0 -> inf/NaN. Do not reintroduce.)
static __device__ __forceinline__ float xor32_max(float x) {
    return fmaxf(x, __shfl_xor(x, 32));
}
static __device__ __forceinline__ float xor32_add(float x) {
    return x + __shfl_xor(x, 32);
}

// ---------------------------------------------------------------------------
// prep: K,V fp32 -> bf16 fragment images (4 KB per 32-key tile).
// Kimg tile: [key 0..31][128B = 64 d bf16]   (MFMA A-operand rows)
// Vimg tile: [d 0..63][64B = 32 keys bf16]   (V^T, PV A-operand rows)
// grid = (NT, NBH), 256 threads.
// ---------------------------------------------------------------------------
__global__ __launch_bounds__(256)
void prep_kernel(const float* __restrict__ K, const float* __restrict__ V,
                 char* __restrict__ Kimg, char* __restrict__ Vimg)
{
    const int t = blockIdx.x, bh = blockIdx.y, tid = threadIdx.x;
    const long tileOff = ((long)bh * NT + t) * 4096;
    const float* kp = K + (long)bh * S_LEN * DH + t * KVT * DH;
    const float* vp = V + (long)bh * S_LEN * DH + t * KVT * DH;

    {   // K rows
        int key = tid >> 3, dc = tid & 7;
        f32x4 x = *(const f32x4*)(kp + key * 64 + dc * 8);
        f32x4 y = *(const f32x4*)(kp + key * 64 + dc * 8 + 4);
        uint4 w;
        w.x = cvtpk_bf16(x[0], x[1]);
        w.y = cvtpk_bf16(x[2], x[3]);
        w.z = cvtpk_bf16(y[0], y[1]);
        w.w = cvtpk_bf16(y[2], y[3]);
        *(uint4*)(Kimg + tileOff + key * 128 + dc * 16) = w;
    }
    {   // V^T rows (4x2 micro-transpose per thread)
        int vdg = tid & 15, vkq = tid >> 4;
        int d0 = vdg * 4, k0 = vkq * 2;
        f32x4 x0 = *(const f32x4*)(vp + k0 * 64 + d0);
        f32x4 x1 = *(const f32x4*)(vp + (k0 + 1) * 64 + d0);
        #pragma unroll
        for (int i = 0; i < 4; ++i)
            *(unsigned*)(Vimg + tileOff + (d0 + i) * 64 + k0 * 2) = cvtpk_bf16(x0[i], x1[i]);
    }
}

// ---------------------------------------------------------------------------
// pre: fz[b] (first pad==0), bias[b][k] = pad?-1e30:0, meanv[bh] (if fz>0).
// grid = NBH blocks, 256 threads.
// ---------------------------------------------------------------------------
__global__ __launch_bounds__(256)
void pre_kernel(const float* __restrict__ V, const int* __restrict__ pad,
                int* __restrict__ fz, float* __restrict__ bias,
                float* __restrict__ meanv)
{
    const int bh = blockIdx.x, b = bh >> 4, tid = threadIdx.x;
    __shared__ int ired[256];
    int local = S_LEN;
    for (int k = tid; k < S_LEN; k += 256) {
        int pv = pad[b * S_LEN + k];
        if (pv == 0 && k < local) local = k;
        if ((bh & 15) == 0) bias[b * S_LEN + k] = pv ? -1e30f : 0.f;
    }
    ired[tid] = local;
    __syncthreads();
    for (int s = 128; s > 0; s >>= 1) {
        if (tid < s) ired[tid] = min(ired[tid], ired[tid + s]);
        __syncthreads();
    }
    const int fzv = ired[0];
    if (tid == 0 && (bh & 15) == 0) fz[b] = fzv;
    if (fzv <= 0) return;                       // uniform branch

    const float* vp = V + (long)bh * S_LEN * DH;
    const int d4 = tid & 15, kp2 = tid >> 4;
    f32x4 acc = (f32x4){0.f, 0.f, 0.f, 0.f};
    for (int k = kp2; k < S_LEN; k += 16)
        acc += *(const f32x4*)(vp + (long)k * DH + d4 * 4);
    __shared__ f32x4 red[16][16];
    red[kp2][d4] = acc;
    __syncthreads();
    #pragma unroll
    for (int s = 8; s >= 1; s >>= 1) {
        if (kp2 < s) red[kp2][d4] += red[kp2 + s][d4];
        __syncthreads();
    }
    if (kp2 == 0)
        *(f32x4*)(meanv + bh * DH + d4 * 4) = red[0][d4] * (1.0f / 2048.0f);
}

// ---------------------------------------------------------------------------
// attn v3: 1-wave blocks, zero LDS, zero barriers. Fragments loaded straight
// from the pre-formatted images into VGPRs, double-banked (t+1 prefetch).
// grid = 2048 x 64 threads. Per-SIMD complementary pairing via (j>>2) flip.
// ---------------------------------------------------------------------------
#define LOADK(dst, tt) do { const char* _p = KB + (long)(tt) * 4096 + lq * 128 + hi * 16; \
    dst[0] = *(const short8*)(_p);       dst[1] = *(const short8*)(_p + 32);  \
    dst[2] = *(const short8*)(_p + 64);  dst[3] = *(const short8*)(_p + 96); } while (0)
#define LOADV(dst, tt) do { const char* _p = VB + (long)(tt) * 4096 + lq * 64 + hi * 16; \
    dst[0] = *(const short8*)(_p);        dst[1] = *(const short8*)(_p + 32); \
    dst[2] = *(const short8*)(_p + 2048); dst[3] = *(const short8*)(_p + 2048 + 32); } while (0)
#define LOADB(dst, tt) do { const float* _p = biasB + (tt) * 32 + hi * 4; \
    dst[0] = *(const f32x4*)(_p);      dst[1] = *(const f32x4*)(_p + 8); \
    dst[2] = *(const f32x4*)(_p + 16); dst[3] = *(const f32x4*)(_p + 24); } while (0)

#define COMPUTE(TT, K_, V_, B_) do {                                          \
    f32x16 s0;                                                                \
    _Pragma("unroll")                                                         \
    for (int g = 0; g < 4; ++g) {                                             \
        f32x4 pb4 = B_[g];                                                    \
        _Pragma("unroll")                                                     \
        for (int i = 0; i < 4; ++i) s0[g * 4 + i] = pb4[i];                   \
    }                                                                         \
    __builtin_amdgcn_s_setprio(1);                                            \
    s0 = __builtin_amdgcn_mfma_f32_32x32x16_bf16(K_[0], bq[0], s0, 0, 0, 0);  \
    s0 = __builtin_amdgcn_mfma_f32_32x32x16_bf16(K_[1], bq[1], s0, 0, 0, 0);  \
    s0 = __builtin_amdgcn_mfma_f32_32x32x16_bf16(K_[2], bq[2], s0, 0, 0, 0);  \
    s0 = __builtin_amdgcn_mfma_f32_32x32x16_bf16(K_[3], bq[3], s0, 0, 0, 0);  \
    __builtin_amdgcn_s_setprio(0);                                            \
    if ((TT) == nkv - 1) {                                                    \
        _Pragma("unroll")                                                     \
        for (int rr = 0; rr < 16; ++rr) {                                     \
            int key_r = (rr & 3) + 8 * (rr >> 2) + 4 * hi;                    \
            if (key_r > lq) s0[rr] = -1e30f;                                  \
        }                                                                     \
    }                                                                         \
    float bm = s0[0];                                                         \
    _Pragma("unroll")                                                         \
    for (int rr = 1; rr < 16; ++rr) bm = fmaxf(bm, s0[rr]);                   \
    bm = xor32_max(bm);                                                       \
    if (__any(bm > m_run + 8.0f)) {                                           \
        float mnew = fmaxf(m_run, bm);                                        \
        float c = exp2f(m_run - mnew);                                        \
        m_run = mnew; l_run *= c;                                             \
        _Pragma("unroll")                                                     \
        for (int rr = 0; rr < 16; ++rr) { o0[rr] *= c; o1[rr] *= c; }         \
    }                                                                         \
    float rs = 0.f;                                                           \
    _Pragma("unroll")                                                         \
    for (int rr = 0; rr < 16; ++rr) {                                         \
        float p = exp2f(s0[rr] - m_run);                                      \
        s0[rr] = p; rs += p;                                                  \
    }                                                                         \
    l_run += xor32_add(rs);                                                   \
    short8 pfr0, pfr1;                                                        \
    {                                                                         \
        unsigned a0 = cvtpk_bf16(s0[0], s0[1]), b0 = cvtpk_bf16(s0[4], s0[5]);\
        asm("v_permlane32_swap_b32 %0, %1" : "+v"(a0), "+v"(b0));             \
        unsigned a1 = cvtpk_bf16(s0[2], s0[3]), b1 = cvtpk_bf16(s0[6], s0[7]);\
        asm("v_permlane32_swap_b32 %0, %1" : "+v"(a1), "+v"(b1));             \
        union { short8 s8; unsigned u[4]; } u;                                \
        u.u[0] = a0; u.u[1] = a1; u.u[2] = b0; u.u[3] = b1;                   \
        pfr0 = u.s8;                                                          \
    }                                                                         \
    {                                                                         \
        unsigned a0 = cvtpk_bf16(s0[8], s0[9]),  b0 = cvtpk_bf16(s0[12], s0[13]); \
        asm("v_permlane32_swap_b32 %0, %1" : "+v"(a0), "+v"(b0));             \
        unsigned a1 = cvtpk_bf16(s0[10], s0[11]), b1 = cvtpk_bf16(s0[14], s0[15]); \
        asm("v_permlane32_swap_b32 %0, %1" : "+v"(a1), "+v"(b1));             \
        union { short8 s8; unsigned u[4]; } u;                                \
        u.u[0] = a0; u.u[1] = a1; u.u[2] = b0; u.u[3] = b1;                   \
        pfr1 = u.s8;                                                          \
    }                                                                         \
    __builtin_amdgcn_s_setprio(1);                                            \
    o0 = __builtin_amdgcn_mfma_f32_32x32x16_bf16(V_[0], pfr0, o0, 0, 0, 0);   \
    o0 = __builtin_amdgcn_mfma_f32_32x32x16_bf16(V_[1], pfr1, o0, 0, 0, 0);   \
    o1 = __builtin_amdgcn_mfma_f32_32x32x16_bf16(V_[2], pfr0, o1, 0, 0, 0);   \
    o1 = __builtin_amdgcn_mfma_f32_32x32x16_bf16(V_[3], pfr1, o1, 0, 0, 0);   \
    __builtin_amdgcn_s_setprio(0);                                            \
} while (0)

__global__ __launch_bounds__(64, 2)
void attn_fwd3(const float* __restrict__ Q, const char* __restrict__ Kimg,
               const char* __restrict__ Vimg, const float* __restrict__ bias,
               float* __restrict__ out)
{
    const int lane = threadIdx.x;
    const int lq = lane & 31, hi = lane >> 5;
    const int gid = blockIdx.x;
    const int j = gid >> 8, r = gid & 255;
    const int bh = r >> 3;
    const int v = (j & 3) * 8 + (r & 7);
    const int bx = (j >> 2) ? 63 - v : v;
    const int q0 = bx * 32;
    const int nkv = bx + 1;
    const long base = (long)bh * S_LEN * DH;

    const char*  KB    = Kimg + (long)bh * NT * 4096;
    const char*  VB    = Vimg + (long)bh * NT * 4096;
    const float* biasB = bias + (bh >> 4) * S_LEN;

    // Q fragments (B operand), scale = (1/8)*log2(e) folded
    const float QS = 0.18033688011112042f;
    short8 bq[4];
    {
        const float* qp = Q + base + (long)(q0 + lq) * DH;
        #pragma unroll
        for (int s = 0; s < 4; ++s) {
            int d0 = s * 16 + hi * 8;
            f32x4 x = *(const f32x4*)(qp + d0);
            f32x4 y = *(const f32x4*)(qp + d0 + 4);
            union { short8 s8; unsigned u[4]; } u;
            u.u[0] = cvtpk_bf16(x[0] * QS, x[1] * QS);
            u.u[1] = cvtpk_bf16(x[2] * QS, x[3] * QS);
            u.u[2] = cvtpk_bf16(y[0] * QS, y[1] * QS);
            u.u[3] = cvtpk_bf16(y[2] * QS, y[3] * QS);
            bq[s] = u.s8;
        }
    }

    f32x16 o0, o1;
    #pragma unroll
    for (int rr = 0; rr < 16; ++rr) { o0[rr] = 0.f; o1[rr] = 0.f; }
    float m_run = -1e30f, l_run = 0.f;

    short8 ka[4], kb_[4], va[4], vb_[4];
    f32x4  ba[4], bb[4];

    LOADB(ba, 0); LOADK(ka, 0); LOADV(va, 0);
    int t = 0;
    for (;;) {
        if (t + 1 < nkv) { LOADB(bb, t + 1); LOADK(kb_, t + 1); LOADV(vb_, t + 1); }
        COMPUTE(t, ka, va, ba);
        ++t; if (t >= nkv) break;
        if (t + 1 < nkv) { LOADB(ba, t + 1); LOADK(ka, t + 1); LOADV(va, t + 1); }
        COMPUTE(t, kb_, vb_, bb);
        ++t; if (t >= nkv) break;
    }

    // epilogue: out[q0+lq][d], d spread over o0 (0..31) / o1 (32..63)
    float invl = 1.0f / l_run;
    float* op = out + base + (long)(q0 + lq) * DH;
    #pragma unroll
    for (int g = 0; g < 4; ++g) {
        f32x4 w0, w1;
        #pragma unroll
        for (int i = 0; i < 4; ++i) {
            w0[i] = o0[g * 4 + i] * invl;
            w1[i] = o1[g * 4 + i] * invl;
        }
        *(f32x4*)(op + g * 8 + hi * 4)      = w0;
        *(f32x4*)(op + 32 + g * 8 + hi * 4) = w1;
    }
}

// ---------------------------------------------------------------------------
// Rows q < fz[b]: reference softmax degenerates to uniform over ALL 2048 keys
// (scores all exactly -1e9 in fp32) -> out = mean(V). Overwrite them.
// ---------------------------------------------------------------------------
__global__ void fixup_kernel(const int* __restrict__ fz, const float* __restrict__ meanv,
                             float* __restrict__ out)
{
    const int bh = blockIdx.x;
    const int b  = bh >> 4;
    const int n  = fz[b];
    if (n <= 0) return;
    __shared__ float mv[DH];
    if (threadIdx.x < DH) mv[threadIdx.x] = meanv[bh * DH + threadIdx.x];
    __syncthreads();
    float* op = out + (long)bh * S_LEN * DH;
    for (int i = threadIdx.x; i < n * DH; i += 256) op[i] = mv[i & 63];
}

extern "C" void kernel_launch(void* const* d_in, const int* in_sizes, int n_in,
                              void* d_out, int out_size, void* d_ws, size_t ws_size,
                              hipStream_t stream)
{
    const float* Q   = (const float*)d_in[0];
    const float* K   = (const float*)d_in[1];
    const float* V   = (const float*)d_in[2];
    const int*   pad = (const int*)d_in[3];
    float* out = (float*)d_out;

    int*   fz    = (int*)d_ws;
    float* meanv = (float*)((char*)d_ws + 256);
    float* bias  = (float*)((char*)d_ws + 8448);
    char*  Kimg  = (char*)d_ws + 32768;
    char*  Vimg  = Kimg + (size_t)NBH * NT * 4096;

    pre_kernel<<<dim3(NBH), dim3(256), 0, stream>>>(V, pad, fz, bias, meanv);
    prep_kernel<<<dim3(NT, NBH), dim3(256), 0, stream>>>(K, V, Kimg, Vimg);
    attn_fwd3<<<dim3(2048), dim3(64), 0, stream>>>(Q, Kimg, Vimg, bias, out);
    fixup_kernel<<<dim3(NBH), dim3(256), 0, stream>>>(fz, meanv, out);
}